// Round 2
// 143.328 us; speedup vs baseline: 1.0341x; 1.0341x over previous
//
#include <hip/hip_runtime.h>
#include <math.h>

// Capsule routing, fused. B=64, I=1024, O=1024 fp32.
//
// Math reduction: routing state collapses to c_k = softmax_o(u*w*vsum), so
// no [B,I,O] tensor is ever materialized.
//
// R6: stage_k/gemm_k spill-free via waves_per_eu; block = 4 waves x same
// i-range, wave owns b -> w shared through L1, no LDS in the hot kernels,
// direct coalesced partial stores.
// R7: reduce_squash 1024 thr/block, 16KB LDS float4 tree.
// R8 (resubmit; prior bench was an infra failure, no signal): stage_k no
// longer recomputes exp2 in pass B. Batch of 4 i's caches m = w*p in 64
// VGPRs across the butterfly; pass B is 64 pure FMAs (no loads, no trans).
// Halves trans-pipe work, removes pass-B L1 streaming. waves_per_eu(3,4)
// gives the 64-reg cache room (<=170 VGPR, 3 waves/SIMD). Bit-identical
// accumulation order vs R7.

#define BB 64
#define II 1024
#define OO 1024
#define EPSF 1e-5f
#define LOG2E 1.44269504088896340736f

__device__ __forceinline__ float wave_sum(float v) {
    #pragma unroll
    for (int off = 32; off > 0; off >>= 1)
        v += __shfl_xor(v, off, 64);
    return v;
}
__device__ __forceinline__ float rfl(float x) {  // force SGPR broadcast
    return __int_as_float(__builtin_amdgcn_readfirstlane(__float_as_int(x)));
}

// ---------------- stage kernel ----------------
// grid = (BB/4) * IBLKS, block = 256. wave -> b = bg*4+wave.
// lane owns o = j*256 + lane*4 + e  (j,e in 0..3).
// Per batch of 4 i's:
//   pass A: stream w rows, compute p = exp2(w*vv*u), per-lane partial
//           denominators, cache m = w*p (4x16 = 64 VGPRs).
//   butterfly: 6 layers x 4 independent chains -> full-o denominators.
//   pass B: ar[k] += m[ii][k] * q_ii   (pure FMA, no memory, no exp2).
template<int IBLKS>
__global__ __launch_bounds__(256)
__attribute__((amdgpu_waves_per_eu(3, 4)))
void stage_k(
    const float* __restrict__ u, const float* __restrict__ w,
    const float* __restrict__ v, float* __restrict__ part)
{
    constexpr int IPB = II / IBLKS;   // i's per block (= per wave)
    constexpr int NB  = IPB / 4;      // batches of 4 i's
    static_assert(IPB % 4 == 0, "need batches of 4");
    const int bg   = blockIdx.x / IBLKS;
    const int iblk = blockIdx.x % IBLKS;
    const int wave = threadIdx.x >> 6;
    const int lane = threadIdx.x & 63;
    const int b    = bg * 4 + wave;
    const float4* w4 = (const float4*)w;
    const float4* v4 = (const float4*)(v + b * OO);

    // v pre-scaled by log2e so logits feed v_exp_f32 directly.
    float vv[16];
    #pragma unroll
    for (int j = 0; j < 4; j++) {
        float4 a = v4[j * 64 + lane];
        vv[j*4+0]=a.x*LOG2E; vv[j*4+1]=a.y*LOG2E;
        vv[j*4+2]=a.z*LOG2E; vv[j*4+3]=a.w*LOG2E;
    }
    float ar[16];
    #pragma unroll
    for (int k = 0; k < 16; k++) ar[k] = 0.f;

    const int i0 = iblk * IPB;
    #pragma unroll 1
    for (int g = 0; g < NB; g++) {
        const int ib = i0 + g * 4;

        // u values -> SGPRs (wave-uniform loads)
        float us[4];
        #pragma unroll
        for (int ii = 0; ii < 4; ii++)
            us[ii] = rfl(u[b * II + ib + ii]);

        // ---- pass A: partial denominators + cached m = w*p ----
        float sA[4];
        float m[4][16];
        #pragma unroll
        for (int ii = 0; ii < 4; ii++) {
            const int i = ib + ii;
            float a0;
            #pragma unroll
            for (int j = 0; j < 4; j++) {
                float4 t = w4[i * 256 + j * 64 + lane];
                float px = __builtin_amdgcn_exp2f((t.x * vv[j*4+0]) * us[ii]);
                float py = __builtin_amdgcn_exp2f((t.y * vv[j*4+1]) * us[ii]);
                float pz = __builtin_amdgcn_exp2f((t.z * vv[j*4+2]) * us[ii]);
                float pw = __builtin_amdgcn_exp2f((t.w * vv[j*4+3]) * us[ii]);
                float s4 = px + py + pz + pw;      // same assoc as R7
                a0 = (j == 0) ? s4 : a0 + s4;
                m[ii][j*4+0] = t.x * px;
                m[ii][j*4+1] = t.y * py;
                m[ii][j*4+2] = t.z * pz;
                m[ii][j*4+3] = t.w * pw;
            }
            sA[ii] = a0;
        }
        // ---- one batched butterfly: 6 layers x 4 independent chains ----
        #pragma unroll
        for (int off = 32; off > 0; off >>= 1) {
            #pragma unroll
            for (int ii = 0; ii < 4; ii++)
                sA[ii] += __shfl_xor(sA[ii], off, 64);
        }
        // q = u * rcp(denom) -> SGPRs
        float qs[4];
        #pragma unroll
        for (int ii = 0; ii < 4; ii++)
            qs[ii] = rfl(us[ii] * __builtin_amdgcn_rcpf(sA[ii]));

        // ---- pass B: pure FMA from cache (no loads, no exp2) ----
        #pragma unroll
        for (int ii = 0; ii < 4; ii++) {
            #pragma unroll
            for (int k = 0; k < 16; k++)
                ar[k] = fmaf(m[ii][k], qs[ii], ar[k]);
        }
    }
    // direct coalesced partial store: no LDS, no barriers
    float4* dst = (float4*)(part + ((size_t)iblk * BB + b) * OO);
    #pragma unroll
    for (int j = 0; j < 4; j++) {
        float4 o;
        o.x = ar[j*4+0]; o.y = ar[j*4+1]; o.z = ar[j*4+2]; o.w = ar[j*4+3];
        dst[j * 64 + lane] = o;
    }
}

// ---------------- partial GEMM (same block structure) ----------------
template<int IBLKS>
__global__ __launch_bounds__(256)
__attribute__((amdgpu_waves_per_eu(4, 4)))
void gemm_k(
    const float* __restrict__ u, const float* __restrict__ w,
    float* __restrict__ part)
{
    constexpr int IPB = II / IBLKS;
    const int bg   = blockIdx.x / IBLKS;
    const int iblk = blockIdx.x % IBLKS;
    const int wave = threadIdx.x >> 6;
    const int lane = threadIdx.x & 63;
    const int b    = bg * 4 + wave;
    const float4* w4 = (const float4*)w;

    float ar[16];
    #pragma unroll
    for (int k = 0; k < 16; k++) ar[k] = 0.f;

    const int i0 = iblk * IPB;
    #pragma unroll 2
    for (int ii = 0; ii < IPB; ii++) {
        const int i = i0 + ii;
        const float ub = rfl(u[b * II + i]);
        #pragma unroll
        for (int j = 0; j < 4; j++) {
            float4 t = w4[i * 256 + j * 64 + lane];
            ar[j*4+0] = fmaf(ub, t.x, ar[j*4+0]);
            ar[j*4+1] = fmaf(ub, t.y, ar[j*4+1]);
            ar[j*4+2] = fmaf(ub, t.z, ar[j*4+2]);
            ar[j*4+3] = fmaf(ub, t.w, ar[j*4+3]);
        }
    }
    float4* dst = (float4*)(part + ((size_t)iblk * BB + b) * OO);
    #pragma unroll
    for (int j = 0; j < 4; j++) {
        float4 o;
        o.x = ar[j*4+0]; o.y = ar[j*4+1]; o.z = ar[j*4+2]; o.w = ar[j*4+3];
        dst[j * 64 + lane] = o;
    }
}

// ---------------- reduce + squash ----------------
// 1024 threads: thread (sl = t>>8, qd = t&255) sums slices
// [sl*nblk/4, (sl+1)*nblk/4) of o-quad qd; 16KB LDS float4 tree; squash
// epilogue on threads<256. mode 0: vbuf=v  1: vbuf+=v  2: out=v
__global__ __launch_bounds__(1024) void reduce_squash(
    const float* __restrict__ part, const float* __restrict__ bias,
    float* __restrict__ vbuf, float* __restrict__ out,
    float scale, int mode, int nblk)
{
    const int b  = blockIdx.x;
    const int t  = threadIdx.x;
    const int qd = t & 255;
    const int sl = t >> 8;
    const int per = nblk >> 2;
    const float4* p4 = (const float4*)part;

    float4 a0 = make_float4(0.f, 0.f, 0.f, 0.f), a1 = a0;
    const int k0 = sl * per;
    #pragma unroll 2
    for (int k = 0; k < per; k += 2) {
        float4 p0 = p4[(size_t)((k0 + k)     * BB + b) * 256 + qd];
        float4 p1 = p4[(size_t)((k0 + k + 1) * BB + b) * 256 + qd];
        a0.x += p0.x; a0.y += p0.y; a0.z += p0.z; a0.w += p0.w;
        a1.x += p1.x; a1.y += p1.y; a1.z += p1.z; a1.w += p1.w;
    }
    a0.x += a1.x; a0.y += a1.y; a0.z += a1.z; a0.w += a1.w;

    __shared__ float4 redq[1024];   // [sl][qd], 16 KB
    redq[t] = a0;
    __syncthreads();

    float ss = 0.f;
    float4 x;
    if (t < 256) {
        float4 r0 = redq[qd], r1 = redq[256 + qd],
               r2 = redq[512 + qd], r3 = redq[768 + qd];
        float4 s;
        s.x = (r0.x + r1.x) + (r2.x + r3.x);
        s.y = (r0.y + r1.y) + (r2.y + r3.y);
        s.z = (r0.z + r1.z) + (r2.z + r3.z);
        s.w = (r0.w + r1.w) + (r2.w + r3.w);
        float4 bb = ((const float4*)bias)[qd];
        x.x = fmaf(s.x, scale, bb.x); x.y = fmaf(s.y, scale, bb.y);
        x.z = fmaf(s.z, scale, bb.z); x.w = fmaf(s.w, scale, bb.w);
        ss = x.x*x.x + x.y*x.y + x.z*x.z + x.w*x.w;
    }
    ss = wave_sum(ss);              // waves 4..15 carry zeros
    __shared__ float red2[16];
    if ((t & 63) == 0) red2[t >> 6] = ss;
    __syncthreads();
    const float tot = (red2[0] + red2[1]) + (red2[2] + red2[3]);

    if (t < 256) {
        const float n = sqrtf(tot);
        const float f = tot / ((1.f + tot) * (n + EPSF));
        float4 vo;
        vo.x = x.x * f; vo.y = x.y * f; vo.z = x.z * f; vo.w = x.w * f;
        if (mode == 0) {
            ((float4*)(vbuf + b * OO))[qd] = vo;
        } else if (mode == 1) {
            float4 pv = ((const float4*)(vbuf + b * OO))[qd];
            pv.x += vo.x; pv.y += vo.y; pv.z += vo.z; pv.w += vo.w;
            ((float4*)(vbuf + b * OO))[qd] = pv;
        } else {
            ((float4*)(out + b * OO))[qd] = vo;
        }
    }
}

template<int IBLKS>
static void run_pipeline(const float* u, const float* w, const float* bias,
                         float* out, void* d_ws, hipStream_t stream)
{
    float* part = (float*)d_ws;
    float* vbuf = part + (size_t)IBLKS * BB * OO;
    dim3 g((BB / 4) * IBLKS), blk(256), rblk(1024);
    // v1 = squash((u@w)/O + bias)
    gemm_k<IBLKS><<<g, blk, 0, stream>>>(u, w, part);
    reduce_squash<<<dim3(BB), rblk, 0, stream>>>(part, bias, vbuf, out,
                                                 1.0f / (float)OO, 0, IBLKS);
    // vsum = v1 + squash(s2 + bias),  s2 via softmax(u*w*v1)
    stage_k<IBLKS><<<g, blk, 0, stream>>>(u, w, vbuf, part);
    reduce_squash<<<dim3(BB), rblk, 0, stream>>>(part, bias, vbuf, out,
                                                 1.0f, 1, IBLKS);
    // out = squash(s3 + bias),  s3 via softmax(u*w*vsum)
    stage_k<IBLKS><<<g, blk, 0, stream>>>(u, w, vbuf, part);
    reduce_squash<<<dim3(BB), rblk, 0, stream>>>(part, bias, vbuf, out,
                                                 1.0f, 2, IBLKS);
}

extern "C" void kernel_launch(void* const* d_in, const int* in_sizes, int n_in,
                              void* d_out, int out_size, void* d_ws, size_t ws_size,
                              hipStream_t stream) {
    (void)in_sizes; (void)n_in; (void)out_size;
    const float* u    = (const float*)d_in[0];
    const float* w    = (const float*)d_in[1];
    const float* bias = (const float*)d_in[2];
    float* out = (float*)d_out;

    const size_t row = (size_t)BB * OO * sizeof(float);  // 256 KB
    if      (ws_size >= 65 * row) run_pipeline<64>(u, w, bias, out, d_ws, stream);
    else if (ws_size >= 33 * row) run_pipeline<32>(u, w, bias, out, d_ws, stream);
    else if (ws_size >= 17 * row) run_pipeline<16>(u, w, bias, out, d_ws, stream);
    else                          run_pipeline<8>(u, w, bias, out, d_ws, stream);
}

// Round 3
// 131.581 us; speedup vs baseline: 1.1265x; 1.0893x over previous
//
#include <hip/hip_runtime.h>
#include <math.h>

// Capsule routing, fused. B=64, I=1024, O=1024 fp32.
//
// Math reduction: routing state collapses to c_k = softmax_o(u*w*vsum), so
// no [B,I,O] tensor is ever materialized.
//
// Timing decomposition (R8 counters): dur_us = ~121us harness workspace
// re-poison fill (3 x 40.3us, fixed) + ~22us our 6 kernels. Optimize ours.
//
// R6: block = 4 waves x same i-range, wave owns b -> w shared through L1,
// XCD-local w slices in L2 (iblk%8 == blockIdx%8), no LDS in hot kernels,
// direct coalesced partial stores.
// R7: reduce_squash 1024 thr/block, 16KB LDS float4 tree.
// R8: stage_k one-pass: cache m = w*p across the butterfly; pass B = pure
// FMA (no recomputed exp2). -4.9us end-to-end.
// R9 (this round): batch-4 -> batch-2 m-cache (32 cache VGPRs) +
// waves_per_eu(4,4). Goal: force VGPR <= 128 so all 1024 blocks are
// co-resident (4 blocks/CU, one dispatch round, no 768-resident tail) and
// 4 waves/SIMD improve trans/VALU cross-wave co-issue. Bit-identical
// accumulation order vs R8 (i ascending, same associativity).

#define BB 64
#define II 1024
#define OO 1024
#define EPSF 1e-5f
#define LOG2E 1.44269504088896340736f

__device__ __forceinline__ float wave_sum(float v) {
    #pragma unroll
    for (int off = 32; off > 0; off >>= 1)
        v += __shfl_xor(v, off, 64);
    return v;
}
__device__ __forceinline__ float rfl(float x) {  // force SGPR broadcast
    return __int_as_float(__builtin_amdgcn_readfirstlane(__float_as_int(x)));
}

// ---------------- stage kernel ----------------
// grid = (BB/4) * IBLKS, block = 256. wave -> b = bg*4+wave.
// lane owns o = j*256 + lane*4 + e  (j,e in 0..3).
// Per batch of 2 i's:
//   pass A: stream w rows, p = exp2(w*vv*u), per-lane partial
//           denominators, cache m = w*p (2x16 = 32 VGPRs).
//   butterfly: 6 layers x 2 independent chains -> full-o denominators.
//   pass B: ar[k] += m[ii][k] * q_ii   (pure FMA, no memory, no exp2).
template<int IBLKS>
__global__ __launch_bounds__(256)
__attribute__((amdgpu_waves_per_eu(4, 4)))
void stage_k(
    const float* __restrict__ u, const float* __restrict__ w,
    const float* __restrict__ v, float* __restrict__ part)
{
    constexpr int IPB = II / IBLKS;   // i's per block (= per wave)
    constexpr int NB  = IPB / 2;      // batches of 2 i's
    static_assert(IPB % 2 == 0, "need batches of 2");
    const int bg   = blockIdx.x / IBLKS;
    const int iblk = blockIdx.x % IBLKS;
    const int wave = threadIdx.x >> 6;
    const int lane = threadIdx.x & 63;
    const int b    = bg * 4 + wave;
    const float4* w4 = (const float4*)w;
    const float4* v4 = (const float4*)(v + b * OO);

    // v pre-scaled by log2e so logits feed v_exp_f32 directly.
    float vv[16];
    #pragma unroll
    for (int j = 0; j < 4; j++) {
        float4 a = v4[j * 64 + lane];
        vv[j*4+0]=a.x*LOG2E; vv[j*4+1]=a.y*LOG2E;
        vv[j*4+2]=a.z*LOG2E; vv[j*4+3]=a.w*LOG2E;
    }
    float ar[16];
    #pragma unroll
    for (int k = 0; k < 16; k++) ar[k] = 0.f;

    const int i0 = iblk * IPB;
    #pragma unroll 1
    for (int g = 0; g < NB; g++) {
        const int ib = i0 + g * 2;

        // u pair -> SGPRs (wave-uniform; ib even so 8B-aligned)
        float2 up = *(const float2*)(u + b * II + ib);
        float us[2];
        us[0] = rfl(up.x);
        us[1] = rfl(up.y);

        // ---- pass A: partial denominators + cached m = w*p ----
        float sA[2];
        float m[2][16];
        #pragma unroll
        for (int ii = 0; ii < 2; ii++) {
            const int i = ib + ii;
            float a0;
            #pragma unroll
            for (int j = 0; j < 4; j++) {
                float4 t = w4[i * 256 + j * 64 + lane];
                float px = __builtin_amdgcn_exp2f((t.x * vv[j*4+0]) * us[ii]);
                float py = __builtin_amdgcn_exp2f((t.y * vv[j*4+1]) * us[ii]);
                float pz = __builtin_amdgcn_exp2f((t.z * vv[j*4+2]) * us[ii]);
                float pw = __builtin_amdgcn_exp2f((t.w * vv[j*4+3]) * us[ii]);
                float s4 = px + py + pz + pw;      // same assoc as R8
                a0 = (j == 0) ? s4 : a0 + s4;
                m[ii][j*4+0] = t.x * px;
                m[ii][j*4+1] = t.y * py;
                m[ii][j*4+2] = t.z * pz;
                m[ii][j*4+3] = t.w * pw;
            }
            sA[ii] = a0;
        }
        // ---- one batched butterfly: 6 layers x 2 independent chains ----
        #pragma unroll
        for (int off = 32; off > 0; off >>= 1) {
            #pragma unroll
            for (int ii = 0; ii < 2; ii++)
                sA[ii] += __shfl_xor(sA[ii], off, 64);
        }
        // q = u * rcp(denom) -> SGPRs
        float qs[2];
        #pragma unroll
        for (int ii = 0; ii < 2; ii++)
            qs[ii] = rfl(us[ii] * __builtin_amdgcn_rcpf(sA[ii]));

        // ---- pass B: pure FMA from cache (no loads, no exp2) ----
        #pragma unroll
        for (int ii = 0; ii < 2; ii++) {
            #pragma unroll
            for (int k = 0; k < 16; k++)
                ar[k] = fmaf(m[ii][k], qs[ii], ar[k]);
        }
    }
    // direct coalesced partial store: no LDS, no barriers
    float4* dst = (float4*)(part + ((size_t)iblk * BB + b) * OO);
    #pragma unroll
    for (int j = 0; j < 4; j++) {
        float4 o;
        o.x = ar[j*4+0]; o.y = ar[j*4+1]; o.z = ar[j*4+2]; o.w = ar[j*4+3];
        dst[j * 64 + lane] = o;
    }
}

// ---------------- partial GEMM (same block structure) ----------------
template<int IBLKS>
__global__ __launch_bounds__(256)
__attribute__((amdgpu_waves_per_eu(4, 4)))
void gemm_k(
    const float* __restrict__ u, const float* __restrict__ w,
    float* __restrict__ part)
{
    constexpr int IPB = II / IBLKS;
    const int bg   = blockIdx.x / IBLKS;
    const int iblk = blockIdx.x % IBLKS;
    const int wave = threadIdx.x >> 6;
    const int lane = threadIdx.x & 63;
    const int b    = bg * 4 + wave;
    const float4* w4 = (const float4*)w;

    float ar[16];
    #pragma unroll
    for (int k = 0; k < 16; k++) ar[k] = 0.f;

    const int i0 = iblk * IPB;
    #pragma unroll 2
    for (int ii = 0; ii < IPB; ii++) {
        const int i = i0 + ii;
        const float ub = rfl(u[b * II + i]);
        #pragma unroll
        for (int j = 0; j < 4; j++) {
            float4 t = w4[i * 256 + j * 64 + lane];
            ar[j*4+0] = fmaf(ub, t.x, ar[j*4+0]);
            ar[j*4+1] = fmaf(ub, t.y, ar[j*4+1]);
            ar[j*4+2] = fmaf(ub, t.z, ar[j*4+2]);
            ar[j*4+3] = fmaf(ub, t.w, ar[j*4+3]);
        }
    }
    float4* dst = (float4*)(part + ((size_t)iblk * BB + b) * OO);
    #pragma unroll
    for (int j = 0; j < 4; j++) {
        float4 o;
        o.x = ar[j*4+0]; o.y = ar[j*4+1]; o.z = ar[j*4+2]; o.w = ar[j*4+3];
        dst[j * 64 + lane] = o;
    }
}

// ---------------- reduce + squash ----------------
// 1024 threads: thread (sl = t>>8, qd = t&255) sums slices
// [sl*nblk/4, (sl+1)*nblk/4) of o-quad qd; 16KB LDS float4 tree; squash
// epilogue on threads<256. mode 0: vbuf=v  1: vbuf+=v  2: out=v
__global__ __launch_bounds__(1024) void reduce_squash(
    const float* __restrict__ part, const float* __restrict__ bias,
    float* __restrict__ vbuf, float* __restrict__ out,
    float scale, int mode, int nblk)
{
    const int b  = blockIdx.x;
    const int t  = threadIdx.x;
    const int qd = t & 255;
    const int sl = t >> 8;
    const int per = nblk >> 2;
    const float4* p4 = (const float4*)part;

    float4 a0 = make_float4(0.f, 0.f, 0.f, 0.f), a1 = a0;
    const int k0 = sl * per;
    #pragma unroll 2
    for (int k = 0; k < per; k += 2) {
        float4 p0 = p4[(size_t)((k0 + k)     * BB + b) * 256 + qd];
        float4 p1 = p4[(size_t)((k0 + k + 1) * BB + b) * 256 + qd];
        a0.x += p0.x; a0.y += p0.y; a0.z += p0.z; a0.w += p0.w;
        a1.x += p1.x; a1.y += p1.y; a1.z += p1.z; a1.w += p1.w;
    }
    a0.x += a1.x; a0.y += a1.y; a0.z += a1.z; a0.w += a1.w;

    __shared__ float4 redq[1024];   // [sl][qd], 16 KB
    redq[t] = a0;
    __syncthreads();

    float ss = 0.f;
    float4 x;
    if (t < 256) {
        float4 r0 = redq[qd], r1 = redq[256 + qd],
               r2 = redq[512 + qd], r3 = redq[768 + qd];
        float4 s;
        s.x = (r0.x + r1.x) + (r2.x + r3.x);
        s.y = (r0.y + r1.y) + (r2.y + r3.y);
        s.z = (r0.z + r1.z) + (r2.z + r3.z);
        s.w = (r0.w + r1.w) + (r2.w + r3.w);
        float4 bb = ((const float4*)bias)[qd];
        x.x = fmaf(s.x, scale, bb.x); x.y = fmaf(s.y, scale, bb.y);
        x.z = fmaf(s.z, scale, bb.z); x.w = fmaf(s.w, scale, bb.w);
        ss = x.x*x.x + x.y*x.y + x.z*x.z + x.w*x.w;
    }
    ss = wave_sum(ss);              // waves 4..15 carry zeros
    __shared__ float red2[16];
    if ((t & 63) == 0) red2[t >> 6] = ss;
    __syncthreads();
    const float tot = (red2[0] + red2[1]) + (red2[2] + red2[3]);

    if (t < 256) {
        const float n = sqrtf(tot);
        const float f = tot / ((1.f + tot) * (n + EPSF));
        float4 vo;
        vo.x = x.x * f; vo.y = x.y * f; vo.z = x.z * f; vo.w = x.w * f;
        if (mode == 0) {
            ((float4*)(vbuf + b * OO))[qd] = vo;
        } else if (mode == 1) {
            float4 pv = ((const float4*)(vbuf + b * OO))[qd];
            pv.x += vo.x; pv.y += vo.y; pv.z += vo.z; pv.w += vo.w;
            ((float4*)(vbuf + b * OO))[qd] = pv;
        } else {
            ((float4*)(out + b * OO))[qd] = vo;
        }
    }
}

template<int IBLKS>
static void run_pipeline(const float* u, const float* w, const float* bias,
                         float* out, void* d_ws, hipStream_t stream)
{
    float* part = (float*)d_ws;
    float* vbuf = part + (size_t)IBLKS * BB * OO;
    dim3 g((BB / 4) * IBLKS), blk(256), rblk(1024);
    // v1 = squash((u@w)/O + bias)
    gemm_k<IBLKS><<<g, blk, 0, stream>>>(u, w, part);
    reduce_squash<<<dim3(BB), rblk, 0, stream>>>(part, bias, vbuf, out,
                                                 1.0f / (float)OO, 0, IBLKS);
    // vsum = v1 + squash(s2 + bias),  s2 via softmax(u*w*v1)
    stage_k<IBLKS><<<g, blk, 0, stream>>>(u, w, vbuf, part);
    reduce_squash<<<dim3(BB), rblk, 0, stream>>>(part, bias, vbuf, out,
                                                 1.0f, 1, IBLKS);
    // out = squash(s3 + bias),  s3 via softmax(u*w*vsum)
    stage_k<IBLKS><<<g, blk, 0, stream>>>(u, w, vbuf, part);
    reduce_squash<<<dim3(BB), rblk, 0, stream>>>(part, bias, vbuf, out,
                                                 1.0f, 2, IBLKS);
}

extern "C" void kernel_launch(void* const* d_in, const int* in_sizes, int n_in,
                              void* d_out, int out_size, void* d_ws, size_t ws_size,
                              hipStream_t stream) {
    (void)in_sizes; (void)n_in; (void)out_size;
    const float* u    = (const float*)d_in[0];
    const float* w    = (const float*)d_in[1];
    const float* bias = (const float*)d_in[2];
    float* out = (float*)d_out;

    const size_t row = (size_t)BB * OO * sizeof(float);  // 256 KB
    if      (ws_size >= 65 * row) run_pipeline<64>(u, w, bias, out, d_ws, stream);
    else if (ws_size >= 33 * row) run_pipeline<32>(u, w, bias, out, d_ws, stream);
    else if (ws_size >= 17 * row) run_pipeline<16>(u, w, bias, out, d_ws, stream);
    else                          run_pipeline<8>(u, w, bias, out, d_ws, stream);
}